// Round 7
// baseline (559.198 us; speedup 1.0000x reference)
//
#include <hip/hip_runtime.h>
#include <math.h>

#define BB 4
#define NN 8000
#define FIN 256
#define DD 128
#define NB 16
#define BS 500
#define KK 8
#define RPB 32
#define CHUNKS (NN/RPB)   /* 250 */
#define ETOT (BB*NN*KK)   /* 256000 */

// ---------------------------------------------------------------------------
// Kernel 1 (fused): encode FFN (256->128 elu->128) + LSH binning + edge tables
// (unchanged from round 5: half-shift weight layout, dbuf weight tiles)
// ---------------------------------------------------------------------------
__global__ __launch_bounds__(256) void k_fused(
    const float* __restrict__ x, const float* __restrict__ w1, const float* __restrict__ b1,
    const float* __restrict__ w2, const float* __restrict__ b2, const float* __restrict__ rot,
    const float* __restrict__ ew1,
    float* __restrict__ pe, float* __restrict__ A, float* __restrict__ Bv,
    int* __restrict__ bin_idx, int* __restrict__ localrank, int* __restrict__ chunkhist)
{
  __shared__ float wsa[32*132];
  __shared__ float wsb[32*132];
  __shared__ float ps[RPB*132];
  __shared__ float ms[RPB*9];
  __shared__ int   bl[RPB];
  const int t = threadIdx.x;
  const int b = blockIdx.x / CHUNKS;
  const int chunk = blockIdx.x % CHUNKS;
  const int row0 = chunk * RPB;
  const int ri = t >> 4;
  const int ci = t & 15;
  const int r0t = ri*2, r1t = ri*2+1;
  const float* xrow0 = x + ((size_t)b*NN + row0 + r0t)*FIN;
  const float* xrow1 = x + ((size_t)b*NN + row0 + r1t)*FIN;
  const int sk = t >> 5, sc4 = t & 31;
  const int ss = (sc4>>4)<<2;
  const int cs = (ci>>3)<<2;

  float acc0[8], acc1[8];
  #pragma unroll
  for (int j=0;j<8;j++){ float bb = b1[ci*8+j]; acc0[j]=bb; acc1[j]=bb; }

  float4 rw0,rw1,rw2,rw3;
  { const float4* wg = (const float4*)w1;
    rw0=wg[t]; rw1=wg[t+256]; rw2=wg[t+512]; rw3=wg[t+768]; }
  int cur = 0;
  for (int kt=0; kt<8; ++kt){
    float* wsc = cur ? wsb : wsa;
    *(float4*)&wsc[(sk   )*132 + sc4*4 + ss] = rw0;
    *(float4*)&wsc[(sk+ 8)*132 + sc4*4 + ss] = rw1;
    *(float4*)&wsc[(sk+16)*132 + sc4*4 + ss] = rw2;
    *(float4*)&wsc[(sk+24)*132 + sc4*4 + ss] = rw3;
    if (kt<7){ const float4* wg = (const float4*)(w1 + (size_t)(kt+1)*32*DD);
      rw0=wg[t]; rw1=wg[t+256]; rw2=wg[t+512]; rw3=wg[t+768]; }
    __syncthreads();
    const float* xp0 = xrow0 + kt*32;
    const float* xp1 = xrow1 + kt*32;
    #pragma unroll
    for (int kc=0;kc<32;kc+=4){
      float4 a0 = *(const float4*)(xp0+kc);
      float4 a1 = *(const float4*)(xp1+kc);
      #pragma unroll
      for (int kk=0;kk<4;kk++){
        float4 wlo = *(const float4*)&wsc[(kc+kk)*132 + ci*8 + cs];
        float4 whi = *(const float4*)&wsc[(kc+kk)*132 + ci*8 + 4 + cs];
        float a0v = ((const float*)&a0)[kk], a1v = ((const float*)&a1)[kk];
        acc0[0]=fmaf(a0v,wlo.x,acc0[0]); acc0[1]=fmaf(a0v,wlo.y,acc0[1]);
        acc0[2]=fmaf(a0v,wlo.z,acc0[2]); acc0[3]=fmaf(a0v,wlo.w,acc0[3]);
        acc0[4]=fmaf(a0v,whi.x,acc0[4]); acc0[5]=fmaf(a0v,whi.y,acc0[5]);
        acc0[6]=fmaf(a0v,whi.z,acc0[6]); acc0[7]=fmaf(a0v,whi.w,acc0[7]);
        acc1[0]=fmaf(a1v,wlo.x,acc1[0]); acc1[1]=fmaf(a1v,wlo.y,acc1[1]);
        acc1[2]=fmaf(a1v,wlo.z,acc1[2]); acc1[3]=fmaf(a1v,wlo.w,acc1[3]);
        acc1[4]=fmaf(a1v,whi.x,acc1[4]); acc1[5]=fmaf(a1v,whi.y,acc1[5]);
        acc1[6]=fmaf(a1v,whi.z,acc1[6]); acc1[7]=fmaf(a1v,whi.w,acc1[7]);
      }
    }
    cur ^= 1;
  }
  #pragma unroll
  for (int j=0;j<8;j++){
    float v0=acc0[j]; ps[r0t*132 + ci*8 + j] = v0>0.f ? v0 : expm1f(v0);
    float v1=acc1[j]; ps[r1t*132 + ci*8 + j] = v1>0.f ? v1 : expm1f(v1);
  }

  float acc20[8], acc21[8];
  #pragma unroll
  for (int j=0;j<8;j++){ float bb = b2[ci*8+j]; acc20[j]=bb; acc21[j]=bb; }
  { const float4* wg = (const float4*)w2;
    rw0=wg[t]; rw1=wg[t+256]; rw2=wg[t+512]; rw3=wg[t+768]; }
  for (int kt=0; kt<4; ++kt){
    float* wsc = cur ? wsb : wsa;
    *(float4*)&wsc[(sk   )*132 + sc4*4 + ss] = rw0;
    *(float4*)&wsc[(sk+ 8)*132 + sc4*4 + ss] = rw1;
    *(float4*)&wsc[(sk+16)*132 + sc4*4 + ss] = rw2;
    *(float4*)&wsc[(sk+24)*132 + sc4*4 + ss] = rw3;
    if (kt<3){ const float4* wg = (const float4*)(w2 + (size_t)(kt+1)*32*DD);
      rw0=wg[t]; rw1=wg[t+256]; rw2=wg[t+512]; rw3=wg[t+768]; }
    __syncthreads();
    #pragma unroll
    for (int kc=0;kc<32;kc+=4){
      float4 a0 = *(const float4*)&ps[r0t*132 + kt*32 + kc];
      float4 a1 = *(const float4*)&ps[r1t*132 + kt*32 + kc];
      #pragma unroll
      for (int kk=0;kk<4;kk++){
        float4 wlo = *(const float4*)&wsc[(kc+kk)*132 + ci*8 + cs];
        float4 whi = *(const float4*)&wsc[(kc+kk)*132 + ci*8 + 4 + cs];
        float a0v = ((const float*)&a0)[kk], a1v = ((const float*)&a1)[kk];
        acc20[0]=fmaf(a0v,wlo.x,acc20[0]); acc20[1]=fmaf(a0v,wlo.y,acc20[1]);
        acc20[2]=fmaf(a0v,wlo.z,acc20[2]); acc20[3]=fmaf(a0v,wlo.w,acc20[3]);
        acc20[4]=fmaf(a0v,whi.x,acc20[4]); acc20[5]=fmaf(a0v,whi.y,acc20[5]);
        acc20[6]=fmaf(a0v,whi.z,acc20[6]); acc20[7]=fmaf(a0v,whi.w,acc20[7]);
        acc21[0]=fmaf(a1v,wlo.x,acc21[0]); acc21[1]=fmaf(a1v,wlo.y,acc21[1]);
        acc21[2]=fmaf(a1v,wlo.z,acc21[2]); acc21[3]=fmaf(a1v,wlo.w,acc21[3]);
        acc21[4]=fmaf(a1v,whi.x,acc21[4]); acc21[5]=fmaf(a1v,whi.y,acc21[5]);
        acc21[6]=fmaf(a1v,whi.z,acc21[6]); acc21[7]=fmaf(a1v,whi.w,acc21[7]);
      }
    }
    cur ^= 1;
  }
  __syncthreads();

  { float* pg0 = pe + ((size_t)b*NN + row0 + r0t)*DD + ci*8;
    float* pg1 = pe + ((size_t)b*NN + row0 + r1t)*DD + ci*8;
    #pragma unroll
    for (int j=0;j<8;j+=4){
      float4 v0 = make_float4(acc20[j],acc20[j+1],acc20[j+2],acc20[j+3]);
      float4 v1 = make_float4(acc21[j],acc21[j+1],acc21[j+2],acc21[j+3]);
      *(float4*)(pg0+j)=v0; *(float4*)&ps[r0t*132 + ci*8 + j]=v0;
      *(float4*)(pg1+j)=v1; *(float4*)&ps[r1t*132 + ci*8 + j]=v1;
    } }

  float aA0[8], aA1[8], aB0[8], aB1[8];
  #pragma unroll
  for (int j=0;j<8;j++){ aA0[j]=0.f; aA1[j]=0.f; aB0[j]=0.f; aB1[j]=0.f; }
  float4 ra0,ra1,ra2,ra3, rb0,rb1,rb2,rb3;
  { const float4* wga = (const float4*)ew1;
    const float4* wgb = (const float4*)(ew1 + (size_t)FIN*DD);
    ra0=wga[t]; ra1=wga[t+256]; ra2=wga[t+512]; ra3=wga[t+768];
    rb0=wgb[t]; rb1=wgb[t+256]; rb2=wgb[t+512]; rb3=wgb[t+768]; }
  for (int kt=0; kt<8; ++kt){
    __syncthreads();
    *(float4*)&wsa[(sk   )*132 + sc4*4 + ss] = ra0;
    *(float4*)&wsa[(sk+ 8)*132 + sc4*4 + ss] = ra1;
    *(float4*)&wsa[(sk+16)*132 + sc4*4 + ss] = ra2;
    *(float4*)&wsa[(sk+24)*132 + sc4*4 + ss] = ra3;
    *(float4*)&wsb[(sk   )*132 + sc4*4 + ss] = rb0;
    *(float4*)&wsb[(sk+ 8)*132 + sc4*4 + ss] = rb1;
    *(float4*)&wsb[(sk+16)*132 + sc4*4 + ss] = rb2;
    *(float4*)&wsb[(sk+24)*132 + sc4*4 + ss] = rb3;
    if (kt<7){
      const float4* wga = (const float4*)(ew1 + (size_t)(kt+1)*32*DD);
      const float4* wgb = (const float4*)(ew1 + (size_t)(FIN + (kt+1)*32)*DD);
      ra0=wga[t]; ra1=wga[t+256]; ra2=wga[t+512]; ra3=wga[t+768];
      rb0=wgb[t]; rb1=wgb[t+256]; rb2=wgb[t+512]; rb3=wgb[t+768]; }
    __syncthreads();
    const float* xp0 = xrow0 + kt*32;
    const float* xp1 = xrow1 + kt*32;
    #pragma unroll
    for (int kc=0;kc<32;kc+=4){
      float4 a0 = *(const float4*)(xp0+kc);
      float4 a1 = *(const float4*)(xp1+kc);
      #pragma unroll
      for (int kk=0;kk<4;kk++){
        float4 alo = *(const float4*)&wsa[(kc+kk)*132 + ci*8 + cs];
        float4 ahi = *(const float4*)&wsa[(kc+kk)*132 + ci*8 + 4 + cs];
        float4 blo = *(const float4*)&wsb[(kc+kk)*132 + ci*8 + cs];
        float4 bhi = *(const float4*)&wsb[(kc+kk)*132 + ci*8 + 4 + cs];
        float a0v = ((const float*)&a0)[kk], a1v = ((const float*)&a1)[kk];
        aA0[0]=fmaf(a0v,alo.x,aA0[0]); aA0[1]=fmaf(a0v,alo.y,aA0[1]);
        aA0[2]=fmaf(a0v,alo.z,aA0[2]); aA0[3]=fmaf(a0v,alo.w,aA0[3]);
        aA0[4]=fmaf(a0v,ahi.x,aA0[4]); aA0[5]=fmaf(a0v,ahi.y,aA0[5]);
        aA0[6]=fmaf(a0v,ahi.z,aA0[6]); aA0[7]=fmaf(a0v,ahi.w,aA0[7]);
        aA1[0]=fmaf(a1v,alo.x,aA1[0]); aA1[1]=fmaf(a1v,alo.y,aA1[1]);
        aA1[2]=fmaf(a1v,alo.z,aA1[2]); aA1[3]=fmaf(a1v,alo.w,aA1[3]);
        aA1[4]=fmaf(a1v,ahi.x,aA1[4]); aA1[5]=fmaf(a1v,ahi.y,aA1[5]);
        aA1[6]=fmaf(a1v,ahi.z,aA1[6]); aA1[7]=fmaf(a1v,ahi.w,aA1[7]);
        aB0[0]=fmaf(a0v,blo.x,aB0[0]); aB0[1]=fmaf(a0v,blo.y,aB0[1]);
        aB0[2]=fmaf(a0v,blo.z,aB0[2]); aB0[3]=fmaf(a0v,blo.w,aB0[3]);
        aB0[4]=fmaf(a0v,bhi.x,aB0[4]); aB0[5]=fmaf(a0v,bhi.y,aB0[5]);
        aB0[6]=fmaf(a0v,bhi.z,aB0[6]); aB0[7]=fmaf(a0v,bhi.w,aB0[7]);
        aB1[0]=fmaf(a1v,blo.x,aB1[0]); aB1[1]=fmaf(a1v,blo.y,aB1[1]);
        aB1[2]=fmaf(a1v,blo.z,aB1[2]); aB1[3]=fmaf(a1v,blo.w,aB1[3]);
        aB1[4]=fmaf(a1v,bhi.x,aB1[4]); aB1[5]=fmaf(a1v,bhi.y,aB1[5]);
        aB1[6]=fmaf(a1v,bhi.z,aB1[6]); aB1[7]=fmaf(a1v,bhi.w,aB1[7]);
      }
    }
  }
  { float* Ag0 = A  + ((size_t)b*NN+row0+r0t)*DD + ci*8;
    float* Ag1 = A  + ((size_t)b*NN+row0+r1t)*DD + ci*8;
    float* Bg0 = Bv + ((size_t)b*NN+row0+r0t)*DD + ci*8;
    float* Bg1 = Bv + ((size_t)b*NN+row0+r1t)*DD + ci*8;
    #pragma unroll
    for (int j=0;j<8;j+=4){
      *(float4*)(Ag0+j)=make_float4(aA0[j],aA0[j+1],aA0[j+2],aA0[j+3]);
      *(float4*)(Ag1+j)=make_float4(aA1[j],aA1[j+1],aA1[j+2],aA1[j+3]);
      *(float4*)(Bg0+j)=make_float4(aB0[j],aB0[j+1],aB0[j+2],aB0[j+3]);
      *(float4*)(Bg1+j)=make_float4(aB1[j],aB1[j+1],aB1[j+2],aB1[j+3]);
    } }

  if (t<128){
    const int r = t>>2, m0 = t&3;
    float s0=0.f, s1=0.f;
    for (int k=0;k<DD;k++){
      float p = ps[r*132+k];
      s0 = fmaf(p, rot[k*100+m0],   s0);
      s1 = fmaf(p, rot[k*100+m0+4], s1);
    }
    ms[r*9+m0]=s0; ms[r*9+m0+4]=s1;
  }
  __syncthreads();
  if (t<RPB){
    float best = ms[t*9+0]; int bi=0;
    #pragma unroll
    for (int m=1;m<16;m++){
      float v = (m<8)? ms[t*9+m] : -ms[t*9+(m-8)];
      if (v>best){best=v;bi=m;}
    }
    bl[t]=bi;
    bin_idx[b*NN+row0+t]=bi;
  }
  __syncthreads();
  if (t<RPB){
    int myb=bl[t]; int rk=0;
    for (int r2=0;r2<t;r2++) rk += (bl[r2]==myb) ? 1 : 0;
    localrank[b*NN+row0+t]=rk;
  }
  if (t<NB){
    int cnt=0;
    #pragma unroll
    for (int r2=0;r2<RPB;r2++) cnt += (bl[r2]==t) ? 1 : 0;
    chunkhist[(b*CHUNKS+chunk)*NB + t] = cnt;
  }
}

// ---------------------------------------------------------------------------
// Kernel 2: fused parallel scan + stable scatter (unchanged)
// ---------------------------------------------------------------------------
__global__ __launch_bounds__(256) void k_scan_scatter(
    const int* __restrict__ bin_idx, const int* __restrict__ localrank,
    const int* __restrict__ chunkhist, int* __restrict__ bs, float* __restrict__ out_bins)
{
  const int b=blockIdx.x, t=threadIdx.x;
  __shared__ int cbase_s[CHUNKS*NB];
  __shared__ int segsum[16*NB];
  __shared__ int start[NB];
  const int m = t&15, s = t>>4;
  const int c0 = s*16, c1 = min(c0+16, CHUNKS);
  { int run=0;
    for (int c=c0;c<c1;c++) run += chunkhist[(b*CHUNKS+c)*NB+m];
    segsum[s*NB+m]=run; }
  __syncthreads();
  if (t<NB){
    int acc=0;
    for (int s2=0;s2<16;s2++){ int v=segsum[s2*NB+t]; segsum[s2*NB+t]=acc; acc+=v; }
    start[t]=acc;
  }
  __syncthreads();
  if (t==0){
    int run=0;
    for (int mm=0;mm<NB;mm++){ int tt=start[mm]; start[mm]=run; run+=tt; }
  }
  __syncthreads();
  { int acc = start[m] + segsum[s*NB+m];
    for (int c=c0;c<c1;c++){
      cbase_s[c*NB+m]=acc;
      acc += chunkhist[(b*CHUNKS+c)*NB+m];
    } }
  __syncthreads();
  for (int row=t; row<NN; row+=256){
    int gi=b*NN+row;
    int chunk=row>>5;
    int bi=bin_idx[gi];
    int pos=cbase_s[chunk*NB+bi]+localrank[gi];
    bs[b*NN+pos]=row;
    out_bins[b*NN+pos]=(float)row;
  }
}

// ---------------------------------------------------------------------------
// Kernel 3: per (batch, bin, 32-row tile) pairwise gaussian + top-8.
// 52 KB LDS -> 3 blocks/CU; XCD-swizzled grid (16 blocks/bin -> one XCD's L2);
// barrier-free main loop with wave-private CT slices. Math bit-identical.
// ---------------------------------------------------------------------------
__global__ __launch_bounds__(256) void k_nn(
    const float* __restrict__ pe, const int* __restrict__ bs,
    float* __restrict__ out_idx, int* __restrict__ e_dst, float* __restrict__ e_val)
{
  __shared__ float RT[32*128];     // 16 KB row tile (later merge vals [128][32])
  __shared__ float CT[4*16*128];   // 32 KB wave-private col slices (later merge idx)
  __shared__ float na_all[512];
  __shared__ int   bsl[BS];
  const int t=threadIdx.x;
  // XCD swizzle: 1024 wgs, 128 consecutive logical blocks per XCD
  const int lb = ((int)blockIdx.x & 7)*128 + ((int)blockIdx.x >> 3);
  const int rt = lb & 15, bin = (lb>>4) & 15, b = lb >> 8;
  const int w = t>>6, lane = t&63;
  const int tr = lane>>2, tc = lane&3;      // thread tile: rows tr*2..+1, cols tc*4..+3
  const float* peb = pe + (size_t)b*NN*DD;

  for (int i=t;i<BS;i+=256) bsl[i]=bs[b*NN + bin*BS + i];
  __syncthreads();

  // squared norms (same sequential accumulation as verified version)
  for (int i=t;i<512;i+=256){
    float s=0.f;
    if (i<BS){
      const float* pr = peb + (size_t)bsl[i]*DD;
      for (int k=0;k<DD;k+=4){
        float4 v=*(const float4*)(pr+k);
        s=fmaf(v.x,v.x,s); s=fmaf(v.y,v.y,s); s=fmaf(v.z,v.z,s); s=fmaf(v.w,v.w,s);
      }
    }
    na_all[i]=s;
  }

  const int r0=rt*32;
  const int nr=min(32, BS-r0);              // 32 or 20
  // stage RT [32][128] with XOR swizzle ((r>>1)&7)<<2 (reads 2-way free)
  #pragma unroll
  for (int p=0;p<4;p++){
    int idx4 = t + p*256;
    int r = idx4>>5, c4 = idx4&31;
    float4 v=make_float4(0.f,0.f,0.f,0.f);
    if (r<nr) v=*(const float4*)(peb + (size_t)bsl[r0+r]*DD + c4*4);
    *(float4*)&RT[r*128 + ((c4*4) ^ (((r>>1)&7)<<2))] = v;
  }

  // issue CT loads for this wave's first subtile (st=w; cols < 64 <= BS)
  const int scol = lane>>2, sch = lane&3;
  float* ctw = CT + w*(16*128);
  const int wswz = (scol&7)<<2;
  float4 creg[8];
  { const float* src = peb + (size_t)bsl[w*16 + scol]*DD;
    #pragma unroll
    for (int p=0;p<8;p++) creg[p]=*(const float4*)(src + (sch+4*p)*4);
  }
  __syncthreads();      // RT + na + bsl visible to all

  #pragma unroll
  for (int p=0;p<8;p++)
    *(float4*)&ctw[scol*128 + ((((sch+4*p)*4)) ^ wswz)] = creg[p];

  float tv[2][8]; int tix[2][8];
  #pragma unroll
  for (int i=0;i<2;i++){
    #pragma unroll
    for (int s=0;s<8;s++){ tv[i][s]=-1e30f; tix[i][s]=0; } }

  const int aswz = (tr&7)<<2;               // rows tr*2+i -> (r>>1)=tr
  int cswz[4];
  #pragma unroll
  for (int j=0;j<4;j++) cswz[j]=(((tc*4+j)&7)<<2);

  for (int q=0;q<8;q++){
    const int c0 = (4*q + w)*16;
    // prefetch next subtile (+64 cols) into regs; hides under GEMM
    if (q<7){
      int cn = c0 + 64 + scol;
      const float* src = peb + (size_t)bsl[(cn<BS)?cn:0]*DD;
      #pragma unroll
      for (int p=0;p<8;p++){
        float4 v=*(const float4*)(src + (sch+4*p)*4);
        creg[p] = (cn<BS) ? v : make_float4(0.f,0.f,0.f,0.f);
      }
    }

    float accm[2][4];
    #pragma unroll
    for (int i=0;i<2;i++){
      #pragma unroll
      for (int j=0;j<4;j++) accm[i][j]=0.f; }
    #pragma unroll 8
    for (int k0=0;k0<DD;k0+=4){
      float4 a4[2], b4[4];
      #pragma unroll
      for (int i=0;i<2;i++) a4[i]=*(const float4*)&RT[(tr*2+i)*128 + (k0 ^ aswz)];
      #pragma unroll
      for (int j=0;j<4;j++) b4[j]=*(const float4*)&ctw[(tc*4+j)*128 + (k0 ^ cswz[j])];
      #pragma unroll
      for (int kk=0;kk<4;kk++){
        #pragma unroll
        for (int i=0;i<2;i++){
          float av=((const float*)&a4[i])[kk];
          #pragma unroll
          for (int j=0;j<4;j++){
            float bvv=((const float*)&b4[j])[kk];
            accm[i][j]=fmaf(av,bvv,accm[i][j]);
          }
        }
      }
    }

    float nrow[2], ncol[4];
    #pragma unroll
    for (int i=0;i<2;i++) nrow[i]=na_all[r0+tr*2+i];
    #pragma unroll
    for (int j=0;j<4;j++) ncol[j]=na_all[c0+tc*4+j];

    #pragma unroll
    for (int i=0;i<2;i++){
      #pragma unroll
      for (int j=0;j<4;j++){
        float t1=nrow[i]-2.f*accm[i][j];
        float d2v=t1+ncol[j];
        float dm=expf(-0.1f*sqrtf(fmaxf(d2v,1e-6f)));
        int c=c0+tc*4+j;
        if (c<BS && dm>tv[i][7]){          // strict > : lax.top_k tie semantics
          tv[i][7]=dm; tix[i][7]=c;
          #pragma unroll
          for (int qq=7;qq>0;qq--){
            if (tv[i][qq]>tv[i][qq-1]){
              float tf=tv[i][qq];tv[i][qq]=tv[i][qq-1];tv[i][qq-1]=tf;
              int   td=tix[i][qq];tix[i][qq]=tix[i][qq-1];tix[i][qq-1]=td;
            }
          }
        }
      }
    }

    // write prefetched slice (within-wave ordering only; no barrier)
    if (q<7){
      #pragma unroll
      for (int p=0;p<8;p++)
        *(float4*)&ctw[scol*128 + ((((sch+4*p)*4)) ^ wswz)] = creg[p];
    }
  }

  __syncthreads();     // all waves done with RT/CT before reuse as scratch
  // dump partials: p=(w*4+tc)*8+s in [0,128); vals->RT[p*32+row], idx->CT
  #pragma unroll
  for (int i=0;i<2;i++){
    const int row=tr*2+i;
    #pragma unroll
    for (int s=0;s<8;s++){
      const int p=(w*4+tc)*8+s;
      RT[p*32 + row]=tv[i][s];
      CT[p*32 + row]=__int_as_float(tix[i][s]);
    }
  }
  __syncthreads();

  if (t<nr){
    float mv[8]; int mi[8];
    #pragma unroll
    for (int s=0;s<8;s++){ mv[s]=-1e30f; mi[s]=0; }
    #pragma unroll 4
    for (int p=0;p<128;p++){
      float v=RT[p*32+t]; int c=__float_as_int(CT[p*32+t]);
      if (v>mv[7] || (v==mv[7] && c<mi[7])){
        mv[7]=v; mi[7]=c;
        #pragma unroll
        for (int qq=7;qq>0;qq--){
          bool sw=(mv[qq]>mv[qq-1]) || (mv[qq]==mv[qq-1] && mi[qq]<mi[qq-1]);
          if (sw){
            float tf=mv[qq];mv[qq]=mv[qq-1];mv[qq-1]=tf;
            int   td=mi[qq];mi[qq]=mi[qq-1];mi[qq-1]=td;
          }
        }
      }
    }
    const int src=bsl[r0+t];
    int dsts[KK]; float vv[KK];
    #pragma unroll
    for (int k2=0;k2<KK;k2++){ dsts[k2]=bsl[mi[k2]]; vv[k2]=mv[k2]; }
    #define CSWAP(a_,b_) { if (dsts[a_]>dsts[b_]){ int td=dsts[a_];dsts[a_]=dsts[b_];dsts[b_]=td; float tf=vv[a_];vv[a_]=vv[b_];vv[b_]=tf; } }
    CSWAP(0,1) CSWAP(2,3) CSWAP(4,5) CSWAP(6,7)
    CSWAP(0,2) CSWAP(1,3) CSWAP(4,6) CSWAP(5,7)
    CSWAP(1,2) CSWAP(5,6)
    CSWAP(0,4) CSWAP(1,5) CSWAP(2,6) CSWAP(3,7)
    CSWAP(2,4) CSWAP(3,5)
    CSWAP(1,2) CSWAP(3,4) CSWAP(5,6)
    #undef CSWAP
    size_t e0=((size_t)b*NN + src)*KK;
    #pragma unroll
    for (int k2=0;k2<KK;k2++){
      out_idx[3*(e0+k2)+0]=(float)b;
      out_idx[3*(e0+k2)+1]=(float)src;
      out_idx[3*(e0+k2)+2]=(float)dsts[k2];
      e_dst[e0+k2]=dsts[k2];
      e_val[e0+k2]=vv[k2];
    }
  }
}

// ---------------------------------------------------------------------------
// Kernel 4: edge MLP. One wave per (b,src) group of 8 edges.
// ---------------------------------------------------------------------------
__global__ __launch_bounds__(256) void k_edge(
    const float* __restrict__ A, const float* __restrict__ Bv,
    const float* __restrict__ ew1, const float* __restrict__ eb1,
    const float* __restrict__ ew2, const float* __restrict__ eb2,
    const int* __restrict__ e_dst, const float* __restrict__ e_val,
    float* __restrict__ out_vals)
{
  const int wid = (int)((blockIdx.x*256u+threadIdx.x)>>6);
  const int lane = threadIdx.x&63;
  if (wid >= BB*NN) return;
  const int b = wid / NN;
  const float2 a2  = *(const float2*)(A   + (size_t)wid*DD + lane*2);
  const float2 wc  = *(const float2*)(ew1 + (size_t)512*DD + lane*2);
  const float2 bb1 = *(const float2*)(eb1 + lane*2);
  const float2 w2v = *(const float2*)(ew2 + lane*2);
  const float  b2s = eb2[0];
  const size_t e0 = (size_t)wid*KK;
  #pragma unroll
  for (int k=0;k<KK;k++){
    int dst = e_dst[e0+k];
    float val = e_val[e0+k];
    const float2 bv = *(const float2*)(Bv + ((size_t)b*NN+dst)*DD + lane*2);
    float h0 = a2.x + bv.x + val*wc.x + bb1.x;  h0 = h0>0.f ? h0 : expm1f(h0);
    float h1 = a2.y + bv.y + val*wc.y + bb1.y;  h1 = h1>0.f ? h1 : expm1f(h1);
    float s = h0*w2v.x + h1*w2v.y;
    #pragma unroll
    for (int off=32; off; off>>=1) s += __shfl_xor(s, off);
    if (lane==k) out_vals[e0+k] = 1.f/(1.f+expf(-(s+b2s)));
  }
}

// ---------------------------------------------------------------------------
extern "C" void kernel_launch(void* const* d_in, const int* in_sizes, int n_in,
                              void* d_out, int out_size, void* d_ws, size_t ws_size,
                              hipStream_t stream)
{
  const float* x    = (const float*)d_in[0];
  const float* ew1v = (const float*)d_in[1];
  const float* eb1v = (const float*)d_in[2];
  const float* ew2v = (const float*)d_in[3];
  const float* eb2v = (const float*)d_in[4];
  const float* gw1  = (const float*)d_in[5];
  const float* gb1  = (const float*)d_in[6];
  const float* gw2  = (const float*)d_in[7];
  const float* gb2  = (const float*)d_in[8];
  const float* rot  = (const float*)d_in[9];

  char* w = (char*)d_ws;
  float* pe   = (float*)w;  w += (size_t)BB*NN*DD*4;
  float* Atab = (float*)w;  w += (size_t)BB*NN*DD*4;
  float* Btab = (float*)w;  w += (size_t)BB*NN*DD*4;
  int*   bin_idx   = (int*)w; w += (size_t)BB*NN*4;
  int*   localrank = (int*)w; w += (size_t)BB*NN*4;
  int*   chunkhist = (int*)w; w += (size_t)BB*CHUNKS*NB*4;
  int*   bs        = (int*)w; w += (size_t)BB*NN*4;
  int*   e_dst     = (int*)w; w += (size_t)ETOT*4;
  float* e_val     = (float*)w; w += (size_t)ETOT*4;

  float* out_idx  = (float*)d_out;
  float* out_vals = out_idx + (size_t)ETOT*3;
  float* out_bins = out_vals + ETOT;

  k_fused<<<dim3(BB*CHUNKS), dim3(256), 0, stream>>>(
      x, ew1v, eb1v, ew2v, eb2v, rot, gw1,
      pe, Atab, Btab, bin_idx, localrank, chunkhist);
  k_scan_scatter<<<dim3(BB), dim3(256), 0, stream>>>(
      bin_idx, localrank, chunkhist, bs, out_bins);
  k_nn<<<dim3(BB*NB*16), dim3(256), 0, stream>>>(pe, bs, out_idx, e_dst, e_val);
  k_edge<<<dim3(BB*NN/4), dim3(256), 0, stream>>>(
      Atab, Btab, gw1, gb1, gw2, gb2, e_dst, e_val, out_vals);
}